// Round 4
// baseline (563.116 us; speedup 1.0000x reference)
//
#include <hip/hip_runtime.h>
#include <hip/hip_bf16.h>
#include <stdint.h>

typedef __bf16 bf16;
typedef __attribute__((ext_vector_type(8))) __bf16 bf16x8;
typedef __attribute__((ext_vector_type(4))) float f32x4;

static constexpr int kTok = 4096;    // B*S
static constexpr int kHid = 1024;
static constexpr int kInter = 4096;

// async global->LDS, 16B/lane. LDS arg must be wave-uniform base; HW adds
// lane*16. Global arg is per-lane.
#define GLDS16(g, l)                                                \
  __builtin_amdgcn_global_load_lds(                                 \
      (const __attribute__((address_space(1))) void*)(g),           \
      (__attribute__((address_space(3))) void*)(l), 16, 0, 0)

// ---------------- fp32 -> bf16 convert of GEMM operands + zero-out --------
// blockIdx.y: 0=X 1=Wg 2=Wu 3=Wd 4=zero(out0)
__global__ void __launch_bounds__(256) k_cvt_all(
    const float* X, const float* Wg, const float* Wu, const float* Wd,
    bf16* Xb, bf16* Wgb, bf16* Wub, bf16* Wdb, float* out0) {
  const long i = ((long)blockIdx.x * 256 + threadIdx.x) * 8;
  if (blockIdx.y == 4) {  // zero out0 (4M floats)
    if (i < (long)kTok * kHid) {
      const f32x4 z = {0.f, 0.f, 0.f, 0.f};
      *(f32x4*)(out0 + i) = z;
      *(f32x4*)(out0 + i + 4) = z;
    }
    return;
  }
  const float* src;
  bf16* dst;
  long n;
  switch (blockIdx.y) {
    case 0: src = X;  dst = Xb;  n = (long)kTok * kHid;   break;
    case 1: src = Wg; dst = Wgb; n = (long)kInter * kHid; break;
    case 2: src = Wu; dst = Wub; n = (long)kInter * kHid; break;
    default: src = Wd; dst = Wdb; n = (long)kHid * kInter; break;
  }
  if (i >= n) return;
  const f32x4 a = *(const f32x4*)(src + i);
  const f32x4 b = *(const f32x4*)(src + i + 4);
  bf16x8 o;
#pragma unroll
  for (int k = 0; k < 4; ++k) { o[k] = (bf16)a[k]; o[4 + k] = (bf16)b[k]; }
  *(bf16x8*)(dst + i) = o;
}

// ---------------- fused: gate+up GEMM (128x64 tile) + router GEMM ---------
// blockIdx.x < 64 : H-tile  H = silu(Xb*Wgb^T) * (Xb*Wub^T)  (bf16 out)
// blockIdx.x == 64: router  out1 = Xf*Wr^T (fp32 staged, direct store)
__global__ void __launch_bounds__(256, 3) gemm_gu_rt(
    const bf16* X, const bf16* Wg, const bf16* Wu,
    const float* Xf, const float* Wr, bf16* H, float* out1) {
  __shared__ bf16 smem[8192];  // 16 KiB union
  const int t = threadIdx.x;
  const int w = t >> 6;
  const int L = t & 63;
  const int la = L & 15;
  const int lk = (L >> 4) * 8;
  const f32x4 fzero = {0.f, 0.f, 0.f, 0.f};

  if (blockIdx.x == 64) {
    // ---- router: C(4096x128) = Xf(4096x1024) * Wr(128x1024)^T, full K ----
    bf16* sA = smem;           // 128x32
    bf16* sB = smem + 4096;    // 128x32
    const long m0 = (long)blockIdx.y * 128;
    const int wm = (w >> 1) * 64;
    const int wn = (w & 1) * 64;
    f32x4 acc[4][4];
#pragma unroll
    for (int i = 0; i < 4; ++i)
#pragma unroll
      for (int j = 0; j < 4; ++j) acc[i][j] = fzero;

    const int c0 = t, c1 = t + 256;
    const long ar0 = m0 + (c0 >> 2), ar1 = m0 + (c1 >> 2);
    const long br0 = (c0 >> 2), br1 = (c1 >> 2);
    const int ko = (c0 & 3) * 8;
    const bf16* sAr = sA + (wm + la) * 32 + lk;
    const bf16* sBr = sB + (wn + la) * 32 + lk;

    for (int kt = 0; kt < 32; ++kt) {
      const long k0 = (long)kt << 5;
      bf16x8 av0, av1, bv0, bv1;
      {
        const f32x4 x0 = *(const f32x4*)(Xf + ar0 * kHid + k0 + ko);
        const f32x4 x1 = *(const f32x4*)(Xf + ar0 * kHid + k0 + ko + 4);
        const f32x4 y0 = *(const f32x4*)(Xf + ar1 * kHid + k0 + ko);
        const f32x4 y1 = *(const f32x4*)(Xf + ar1 * kHid + k0 + ko + 4);
        const f32x4 p0 = *(const f32x4*)(Wr + br0 * kHid + k0 + ko);
        const f32x4 p1 = *(const f32x4*)(Wr + br0 * kHid + k0 + ko + 4);
        const f32x4 q0 = *(const f32x4*)(Wr + br1 * kHid + k0 + ko);
        const f32x4 q1 = *(const f32x4*)(Wr + br1 * kHid + k0 + ko + 4);
#pragma unroll
        for (int i = 0; i < 4; ++i) {
          av0[i] = (bf16)x0[i]; av0[4 + i] = (bf16)x1[i];
          av1[i] = (bf16)y0[i]; av1[4 + i] = (bf16)y1[i];
          bv0[i] = (bf16)p0[i]; bv0[4 + i] = (bf16)p1[i];
          bv1[i] = (bf16)q0[i]; bv1[4 + i] = (bf16)q1[i];
        }
      }
      __syncthreads();
      *(bf16x8*)(sA + c0 * 8) = av0;
      *(bf16x8*)(sA + c1 * 8) = av1;
      *(bf16x8*)(sB + c0 * 8) = bv0;
      *(bf16x8*)(sB + c1 * 8) = bv1;
      __syncthreads();
      bf16x8 af[4], bfm[4];
#pragma unroll
      for (int i = 0; i < 4; ++i) {
        af[i] = *(const bf16x8*)(sAr + i * 512);
        bfm[i] = *(const bf16x8*)(sBr + i * 512);
      }
#pragma unroll
      for (int i = 0; i < 4; ++i)
#pragma unroll
        for (int j = 0; j < 4; ++j)
          acc[i][j] = __builtin_amdgcn_mfma_f32_16x16x32_bf16(
              af[i], bfm[j], acc[i][j], 0, 0, 0);
    }
    const long col0 = wn + la;
    const long row0 = m0 + wm + (L >> 4) * 4;
#pragma unroll
    for (int i = 0; i < 4; ++i)
#pragma unroll
      for (int j = 0; j < 4; ++j)
#pragma unroll
        for (int r = 0; r < 4; ++r)
          out1[(row0 + i * 16 + r) * 128 + col0 + j * 16] = acc[i][j][r];
    return;
  }

  // ---- gate+up: block tile 128(m) x 64(n), wave tile 64x32, 12 waves/CU ---
  bf16* sX = smem;           // 128x32  (8 KiB)
  bf16* sG = smem + 4096;    // 64x32   (4 KiB)
  bf16* sU = sG + 2048;      // 64x32   (4 KiB)
  const long m0 = (long)blockIdx.y * 128;
  const long n0 = (long)blockIdx.x * 64;
  const int wm = (w >> 1) * 64;
  const int wn = (w & 1) * 32;

  f32x4 accG[4][2], accU[4][2];
#pragma unroll
  for (int i = 0; i < 4; ++i)
#pragma unroll
    for (int j = 0; j < 2; ++j) { accG[i][j] = fzero; accU[i][j] = fzero; }

  const int r0 = t >> 2;          // 0..63
  const int ko = (t & 3) * 8;
  const bf16* gX0 = X + (m0 + r0) * kHid + ko;          // rows 0..63
  const bf16* gX1 = gX0 + (long)64 * kHid;              // rows 64..127
  const bf16* gG0 = Wg + (n0 + r0) * kHid + ko;         // 64 rows
  const bf16* gU0 = Wu + (n0 + r0) * kHid + ko;
  bf16* lX0 = sX + w * 512;       // wave-uniform LDS bases
  bf16* lX1 = sX + 2048 + w * 512;
  bf16* lG = sG + w * 512;
  bf16* lU = sU + w * 512;

  const bf16* sXr = sX + (wm + la) * 32 + lk;
  const bf16* sGr = sG + (wn + la) * 32 + lk;
  const bf16* sUr = sU + (wn + la) * 32 + lk;

  for (int kt = 0; kt < 32; ++kt) {
    const long k0 = (long)kt << 5;
    GLDS16(gX0 + k0, lX0);
    GLDS16(gX1 + k0, lX1);
    GLDS16(gG0 + k0, lG);
    GLDS16(gU0 + k0, lU);
    __syncthreads();  // drains vmcnt -> tiles resident
    bf16x8 af[4], bg[2], bu[2];
#pragma unroll
    for (int i = 0; i < 4; ++i) af[i] = *(const bf16x8*)(sXr + i * 512);
#pragma unroll
    for (int j = 0; j < 2; ++j) {
      bg[j] = *(const bf16x8*)(sGr + j * 512);
      bu[j] = *(const bf16x8*)(sUr + j * 512);
    }
#pragma unroll
    for (int i = 0; i < 4; ++i)
#pragma unroll
      for (int j = 0; j < 2; ++j) {
        accG[i][j] = __builtin_amdgcn_mfma_f32_16x16x32_bf16(
            af[i], bg[j], accG[i][j], 0, 0, 0);
        accU[i][j] = __builtin_amdgcn_mfma_f32_16x16x32_bf16(
            af[i], bu[j], accU[i][j], 0, 0, 0);
      }
    __syncthreads();  // all waves done reading before next overwrite
  }
  const long col0 = n0 + wn + la;
  const long row0 = m0 + wm + (L >> 4) * 4;
#pragma unroll
  for (int i = 0; i < 4; ++i)
#pragma unroll
    for (int j = 0; j < 2; ++j)
#pragma unroll
      for (int r = 0; r < 4; ++r) {
        const float g = accG[i][j][r];
        const float u = accU[i][j][r];
        H[(row0 + i * 16 + r) * kInter + col0 + j * 16] =
            (bf16)(g / (1.f + __expf(-g)) * u);
      }
}

// ---------------- fused: down GEMM (split-K=4, atomic) + route_expert -----
// blockIdx.x < 1024 : out0 += H*Wd^T tile (atomic f32)
// blockIdx.x >= 1024: routing + experts, atomic accumulate into out0
__global__ void __launch_bounds__(256, 3) gemm_down_re(
    const bf16* Hs, const bf16* Wd, const float* logits, const float* Xf,
    const float* dE, const float* uE, float* out0) {
  __shared__ char smem[16384];
  const int bid = blockIdx.x;
  const int t = threadIdx.x;
  const int w = t >> 6;
  const int L = t & 63;

  if (bid < 1024) {
    // ---- down: C tile (by*128, bx*128), K-quarter bz ----
    constexpr int K = kInter, N = kHid;
    bf16* sA = (bf16*)smem;          // 128x32
    bf16* sB = (bf16*)smem + 4096;   // 128x32
    const int bx = bid & 7;
    const int by = (bid >> 3) & 31;
    const int bz = bid >> 8;
    const long m0 = (long)by * 128;
    const long n0 = (long)bx * 128;
    const long zb = (long)bz * 1024;
    const int wm = (w >> 1) * 64;
    const int wn = (w & 1) * 64;
    const int la = L & 15;
    const int lk = (L >> 4) * 8;

    f32x4 acc[4][4];
    const f32x4 fzero = {0.f, 0.f, 0.f, 0.f};
#pragma unroll
    for (int i = 0; i < 4; ++i)
#pragma unroll
      for (int j = 0; j < 4; ++j) acc[i][j] = fzero;

    const int r0 = t >> 2;
    const int ko = (t & 3) * 8;
    const bf16* gA0 = Hs + (m0 + r0) * K + zb + ko;
    const bf16* gA1 = gA0 + (long)64 * K;
    const bf16* gB0 = Wd + (n0 + r0) * K + zb + ko;
    const bf16* gB1 = gB0 + (long)64 * K;
    bf16* lA0 = sA + w * 512;
    bf16* lA1 = sA + 2048 + w * 512;
    bf16* lB0 = sB + w * 512;
    bf16* lB1 = sB + 2048 + w * 512;
    const bf16* sAr = sA + (wm + la) * 32 + lk;
    const bf16* sBr = sB + (wn + la) * 32 + lk;

    for (int kt = 0; kt < 32; ++kt) {
      const long k0 = (long)kt << 5;
      GLDS16(gA0 + k0, lA0);
      GLDS16(gA1 + k0, lA1);
      GLDS16(gB0 + k0, lB0);
      GLDS16(gB1 + k0, lB1);
      __syncthreads();
      bf16x8 af[4], bfm[4];
#pragma unroll
      for (int i = 0; i < 4; ++i) {
        af[i] = *(const bf16x8*)(sAr + i * 512);
        bfm[i] = *(const bf16x8*)(sBr + i * 512);
      }
#pragma unroll
      for (int i = 0; i < 4; ++i)
#pragma unroll
        for (int j = 0; j < 4; ++j)
          acc[i][j] = __builtin_amdgcn_mfma_f32_16x16x32_bf16(
              af[i], bfm[j], acc[i][j], 0, 0, 0);
      __syncthreads();
    }
    const long col0 = n0 + wn + la;
    const long row0 = m0 + wm + (L >> 4) * 4;
#pragma unroll
    for (int i = 0; i < 4; ++i)
#pragma unroll
      for (int j = 0; j < 4; ++j)
#pragma unroll
        for (int r = 0; r < 4; ++r)
          __hip_atomic_fetch_add(
              &out0[(row0 + i * 16 + r) * N + col0 + j * 16], acc[i][j][r],
              __ATOMIC_RELAXED, __HIP_MEMORY_SCOPE_AGENT);
    return;
  }

  // ---- route_expert (atomic accumulate into out0) ----
  float (*s_vals)[128] = (float (*)[128])smem;           // 2 KiB
  int (*s_idx)[128] = (int (*)[128])(smem + 2048);       // 2 KiB
  const int j = (bid - 1024) * 4 + w;

  const int half = (j & 1) * 64;
  const int rx = j >> 1;
  const float vx = logits[(long)rx * 128 + half + L];
  const float vy = logits[(long)(2048 + rx) * 128 + half + L];

  int rkx = 0, rky = 0;
  for (int m = 0; m < 64; ++m) {
    const float mx = __shfl(vx, m);
    const float my = __shfl(vy, m);
    rkx += (mx > vx) || (mx == vx && m < L);
    rky += (my > vy) || (my == vy && m < L);
  }
  rkx &= 63;
  rky &= 63;
  s_vals[w][rkx] = vx;
  s_idx[w][rkx] = L;
  s_vals[w][64 + rky] = vy;
  s_idx[w][64 + rky] = L;
  __syncthreads();

  int p = 0, q = 0;
  const bool valid = (L < 20);
  if (L < 8)       { p = L;      q = 0; }
  else if (L < 12) { p = L - 8;  q = 1; }
  else if (L < 14) { p = L - 12; q = 2; }
  else if (L < 16) { p = L - 14; q = 3; }
  else if (L < 20) { p = 0;      q = L - 12; }
  const float kNegBig = -3.0e38f;
  float myv = valid ? (s_vals[w][p] + s_vals[w][64 + q]) : kNegBig;
  int mypos = valid ? (p * 64 + q) : 0x7fffffff;

  float topv[8];
  int tope[8];
#pragma unroll
  for (int r = 0; r < 8; ++r) {
    float bv = myv;
    int bp = mypos;
#pragma unroll
    for (int d = 32; d > 0; d >>= 1) {
      const float ov = __shfl_xor(bv, d);
      const int op = __shfl_xor(bp, d);
      if (ov > bv || (ov == bv && op < bp)) { bv = ov; bp = op; }
    }
    topv[r] = bv;
    const int pp = (bp >> 6) & 127, qq = bp & 63;
    tope[r] = (s_idx[w][pp] * 64 + s_idx[w][64 + qq]) & 4095;
    if (mypos == bp) myv = kNegBig;
  }

  float e[8], wsum = 0.f;
#pragma unroll
  for (int r = 0; r < 8; ++r) {
    e[r] = __expf(topv[r] - topv[0]);
    wsum += e[r];
  }
  const float winv = 1.f / wsum;

  const long xoff = (long)j * kHid + L * 16;
  float xv[16], acc[16];
#pragma unroll
  for (int v4 = 0; v4 < 4; ++v4) {
    const f32x4 xl = *(const f32x4*)(Xf + xoff + v4 * 4);
#pragma unroll
    for (int i = 0; i < 4; ++i) { xv[v4 * 4 + i] = xl[i]; acc[v4 * 4 + i] = 0.f; }
  }

  for (int r = 0; r < 8; ++r) {
    const long eo = (long)tope[r] * kHid + L * 16;
    float d = 0.f;
#pragma unroll
    for (int v4 = 0; v4 < 4; ++v4) {
      const f32x4 dl = *(const f32x4*)(dE + eo + v4 * 4);
#pragma unroll
      for (int i = 0; i < 4; ++i) d += dl[i] * xv[v4 * 4 + i];
    }
#pragma unroll
    for (int dd = 32; dd > 0; dd >>= 1) d += __shfl_xor(d, dd);
    const float ew = d / (1.f + __expf(-d)) * (e[r] * winv);
#pragma unroll
    for (int v4 = 0; v4 < 4; ++v4) {
      const f32x4 ul = *(const f32x4*)(uE + eo + v4 * 4);
#pragma unroll
      for (int i = 0; i < 4; ++i) acc[v4 * 4 + i] += ew * ul[i];
    }
  }

  float* po = out0 + xoff;
#pragma unroll
  for (int v4 = 0; v4 < 4; ++v4)
#pragma unroll
    for (int i = 0; i < 4; ++i)
      __hip_atomic_fetch_add(po + v4 * 4 + i, acc[v4 * 4 + i],
                             __ATOMIC_RELAXED, __HIP_MEMORY_SCOPE_AGENT);
}

extern "C" void kernel_launch(void* const* d_in, const int* in_sizes, int n_in,
                              void* d_out, int out_size, void* d_ws,
                              size_t ws_size, hipStream_t stream) {
  (void)in_sizes; (void)n_in; (void)out_size; (void)ws_size;
  const float* X  = (const float*)d_in[0];
  const float* Wg = (const float*)d_in[1];
  const float* Wu = (const float*)d_in[2];
  const float* Wd = (const float*)d_in[3];
  const float* Wr = (const float*)d_in[4];
  const float* dE = (const float*)d_in[5];
  const float* uE = (const float*)d_in[6];

  float* out0 = (float*)d_out;                  // (4096,1024) final
  float* out1 = out0 + (size_t)kTok * kHid;     // (2,4096,64) router logits

  // workspace layout (64 MiB):
  //   wsH : 32 MiB H bf16
  //   Xb/Wgb/Wub/Wdb : 8 MiB each
  bf16* wsH = (bf16*)d_ws;
  bf16* Xb  = wsH + (size_t)kTok * kInter;
  bf16* Wgb = Xb  + (size_t)kTok * kHid;
  bf16* Wub = Wgb + (size_t)kInter * kHid;
  bf16* Wdb = Wub + (size_t)kInter * kHid;

  dim3 blk(256);
  // 1) convert operands to bf16 + zero out0
  k_cvt_all<<<dim3(2048, 5), blk, 0, stream>>>(X, Wg, Wu, Wd,
                                               Xb, Wgb, Wub, Wdb, out0);
  // 2) H = silu(X*Wg^T)*(X*Wu^T)  (2048 blocks) + router -> out1 (32 blocks)
  gemm_gu_rt<<<dim3(65, 32), blk, 0, stream>>>(Xb, Wgb, Wub, X, Wr, wsH, out1);
  // 3) out0 += H*Wd^T (split-K=4, 1024 blocks) + route_expert (1024 blocks)
  gemm_down_re<<<dim3(2048), blk, 0, stream>>>(wsH, Wdb, out1, X, dE, uE, out0);
}

// Round 6
// 348.925 us; speedup vs baseline: 1.6139x; 1.6139x over previous
//
#include <hip/hip_runtime.h>
#include <hip/hip_bf16.h>
#include <stdint.h>

typedef __bf16 bf16;
typedef __attribute__((ext_vector_type(8))) __bf16 bf16x8;
typedef __attribute__((ext_vector_type(4))) float f32x4;

static constexpr int kTok = 4096;    // B*S
static constexpr int kHid = 1024;
static constexpr int kInter = 4096;

// async global->LDS, 16B/lane. LDS arg must be wave-uniform base; HW adds
// lane*16. Global arg is per-lane.
#define GLDS16(g, l)                                                \
  __builtin_amdgcn_global_load_lds(                                 \
      (const __attribute__((address_space(1))) void*)(g),           \
      (__attribute__((address_space(3))) void*)(l), 16, 0, 0)

// ---------------- fp32 -> bf16 convert of all GEMM operands ---------------
// blockIdx.y: 0=X 1=Wg 2=Wu 3=Wd 4=Wr
__global__ void __launch_bounds__(256) k_cvt_all(
    const float* X, const float* Wg, const float* Wu, const float* Wd,
    const float* Wr, bf16* Xb, bf16* Wgb, bf16* Wub, bf16* Wdb, bf16* Wrb) {
  const long i = ((long)blockIdx.x * 256 + threadIdx.x) * 8;
  const float* src;
  bf16* dst;
  long n;
  switch (blockIdx.y) {
    case 0: src = X;  dst = Xb;  n = (long)kTok * kHid;   break;
    case 1: src = Wg; dst = Wgb; n = (long)kInter * kHid; break;
    case 2: src = Wu; dst = Wub; n = (long)kInter * kHid; break;
    case 3: src = Wd; dst = Wdb; n = (long)kHid * kInter; break;
    default: src = Wr; dst = Wrb; n = 128L * kHid;        break;
  }
  if (i >= n) return;
  const f32x4 a = *(const f32x4*)(src + i);
  const f32x4 b = *(const f32x4*)(src + i + 4);
  bf16x8 o;
#pragma unroll
  for (int k = 0; k < 4; ++k) { o[k] = (bf16)a[k]; o[4 + k] = (bf16)b[k]; }
  *(bf16x8*)(dst + i) = o;
}

// ---------------- router GEMM (bf16, full-K, plain store) -----------------
// out1(4096x128) = Xb(4096x1024) * Wrb(128x1024)^T.  Tile 64(m)x128(n),
// grid 64 blocks, 4 waves (wave-tile 32x64), no atomics.
__global__ void __launch_bounds__(256, 2) gemm_router(
    const bf16* A, const bf16* Bm, float* outF) {
  constexpr int K = kHid, N = 128;
  __shared__ bf16 sA[64 * 32];    // 4 KiB
  __shared__ bf16 sB[128 * 32];   // 8 KiB
  const int t = threadIdx.x;
  const int w = t >> 6;
  const int L = t & 63;
  const long m0 = (long)blockIdx.x * 64;
  const int wm = (w >> 1) * 32;   // 2 M-strips of 32
  const int wn = (w & 1) * 64;    // 2 N-strips of 64

  f32x4 acc[2][4];
  const f32x4 fzero = {0.f, 0.f, 0.f, 0.f};
#pragma unroll
  for (int i = 0; i < 2; ++i)
#pragma unroll
    for (int j = 0; j < 4; ++j) acc[i][j] = fzero;

  const int r0 = t >> 2;          // 0..63
  const int ko = (t & 3) * 8;
  const bf16* gA0 = A + (m0 + r0) * K + ko;       // 64 rows, 1 call
  const bf16* gB0 = Bm + (long)r0 * K + ko;       // rows 0..63
  const bf16* gB1 = gB0 + (long)64 * K;           // rows 64..127
  bf16* lA0 = sA + w * 512;
  bf16* lB0 = sB + w * 512;
  bf16* lB1 = sB + 2048 + w * 512;

  const int la = L & 15;
  const int lk = (L >> 4) * 8;
  const bf16* sAr = sA + (wm + la) * 32 + lk;
  const bf16* sBr = sB + (wn + la) * 32 + lk;

  for (int kt = 0; kt < K / 32; ++kt) {
    const long k0 = (long)kt << 5;
    GLDS16(gA0 + k0, lA0);
    GLDS16(gB0 + k0, lB0);
    GLDS16(gB1 + k0, lB1);
    __syncthreads();  // drains vmcnt -> tiles resident
    bf16x8 af[2], bfm[4];
#pragma unroll
    for (int i = 0; i < 2; ++i) af[i] = *(const bf16x8*)(sAr + i * 512);
#pragma unroll
    for (int j = 0; j < 4; ++j) bfm[j] = *(const bf16x8*)(sBr + j * 512);
#pragma unroll
    for (int i = 0; i < 2; ++i)
#pragma unroll
      for (int j = 0; j < 4; ++j)
        acc[i][j] = __builtin_amdgcn_mfma_f32_16x16x32_bf16(af[i], bfm[j],
                                                            acc[i][j], 0, 0, 0);
    __syncthreads();
  }
  const long col0 = wn + la;
  const long row0 = m0 + wm + (L >> 4) * 4;
#pragma unroll
  for (int i = 0; i < 2; ++i)
#pragma unroll
    for (int j = 0; j < 4; ++j)
#pragma unroll
      for (int r = 0; r < 4; ++r)
        outF[(row0 + i * 16 + r) * N + col0 + j * 16] = acc[i][j][r];
}

// ---------------- fused gate+up+silu (bf16, R1-verified structure) --------
// H(4096x4096) = silu(Xb*Wgb^T) * (Xb*Wub^T), bf16 out to ws.
__global__ void __launch_bounds__(256, 2) gemm_gu(
    const bf16* X, const bf16* Wg, const bf16* Wu, bf16* H) {
  constexpr int K = kHid, N = kInter;
  __shared__ bf16 sX[128 * 32];
  __shared__ bf16 sG[128 * 32];
  __shared__ bf16 sU[128 * 32];
  const int t = threadIdx.x;
  const int w = t >> 6;
  const int L = t & 63;
  const long m0 = (long)blockIdx.y * 128;
  const long n0 = (long)blockIdx.x * 128;
  const int wm = (w >> 1) * 64;
  const int wn = (w & 1) * 64;

  f32x4 accG[4][4], accU[4][4];
  const f32x4 fzero = {0.f, 0.f, 0.f, 0.f};
#pragma unroll
  for (int i = 0; i < 4; ++i)
#pragma unroll
    for (int j = 0; j < 4; ++j) { accG[i][j] = fzero; accU[i][j] = fzero; }

  const int r0 = t >> 2;
  const int ko = (t & 3) * 8;
  const bf16* gX0 = X + (m0 + r0) * K + ko;
  const bf16* gX1 = gX0 + (long)64 * K;
  const bf16* gG0 = Wg + (n0 + r0) * K + ko;
  const bf16* gG1 = gG0 + (long)64 * K;
  const bf16* gU0 = Wu + (n0 + r0) * K + ko;
  const bf16* gU1 = gU0 + (long)64 * K;
  bf16* lX0 = sX + w * 512;
  bf16* lX1 = sX + 2048 + w * 512;
  bf16* lG0 = sG + w * 512;
  bf16* lG1 = sG + 2048 + w * 512;
  bf16* lU0 = sU + w * 512;
  bf16* lU1 = sU + 2048 + w * 512;

  const int la = L & 15;
  const int lk = (L >> 4) * 8;
  const bf16* sXr = sX + (wm + la) * 32 + lk;
  const bf16* sGr = sG + (wn + la) * 32 + lk;
  const bf16* sUr = sU + (wn + la) * 32 + lk;

  for (int kt = 0; kt < K / 32; ++kt) {
    const long k0 = (long)kt << 5;
    GLDS16(gX0 + k0, lX0);
    GLDS16(gX1 + k0, lX1);
    GLDS16(gG0 + k0, lG0);
    GLDS16(gG1 + k0, lG1);
    GLDS16(gU0 + k0, lU0);
    GLDS16(gU1 + k0, lU1);
    __syncthreads();
    bf16x8 af[4], bg[4], bu[4];
#pragma unroll
    for (int i = 0; i < 4; ++i) {
      af[i] = *(const bf16x8*)(sXr + i * 512);
      bg[i] = *(const bf16x8*)(sGr + i * 512);
      bu[i] = *(const bf16x8*)(sUr + i * 512);
    }
#pragma unroll
    for (int i = 0; i < 4; ++i)
#pragma unroll
      for (int j = 0; j < 4; ++j) {
        accG[i][j] = __builtin_amdgcn_mfma_f32_16x16x32_bf16(af[i], bg[j],
                                                             accG[i][j], 0, 0, 0);
        accU[i][j] = __builtin_amdgcn_mfma_f32_16x16x32_bf16(af[i], bu[j],
                                                             accU[i][j], 0, 0, 0);
      }
    __syncthreads();
  }
  const long col0 = n0 + wn + la;
  const long row0 = m0 + wm + (L >> 4) * 4;
#pragma unroll
  for (int i = 0; i < 4; ++i)
#pragma unroll
    for (int j = 0; j < 4; ++j)
#pragma unroll
      for (int r = 0; r < 4; ++r) {
        const float g = accG[i][j][r];
        const float u = accU[i][j][r];
        H[(row0 + i * 16 + r) * N + col0 + j * 16] =
            (bf16)(g / (1.f + __expf(-g)) * u);
      }
}

// ---------------- down GEMM (bf16, full-K, plain store) -------------------
// out0(4096x1024) = H(4096x4096,bf16) * Wdb(1024x4096)^T.
// Tile 128(m)x64(n), grid (16,32)=512 blocks @2/CU, no atomics, no zeroing.
__global__ void __launch_bounds__(256, 2) gemm_down(
    const bf16* Hs, const bf16* Wd, float* out0) {
  constexpr int K = kInter, N = kHid;
  __shared__ bf16 sA[128 * 32];   // 8 KiB
  __shared__ bf16 sB[64 * 32];    // 4 KiB
  const int t = threadIdx.x;
  const int w = t >> 6;
  const int L = t & 63;
  const long m0 = (long)blockIdx.y * 128;
  const long n0 = (long)blockIdx.x * 64;
  const int wm = (w >> 1) * 64;   // 2 M-strips of 64
  const int wn = (w & 1) * 32;    // 2 N-strips of 32

  f32x4 acc[4][2];
  const f32x4 fzero = {0.f, 0.f, 0.f, 0.f};
#pragma unroll
  for (int i = 0; i < 4; ++i)
#pragma unroll
    for (int j = 0; j < 2; ++j) acc[i][j] = fzero;

  const int r0 = t >> 2;
  const int ko = (t & 3) * 8;
  const bf16* gA0 = Hs + (m0 + r0) * K + ko;      // rows 0..63
  const bf16* gA1 = gA0 + (long)64 * K;           // rows 64..127
  const bf16* gB0 = Wd + (n0 + r0) * K + ko;      // 64 rows, 1 call
  bf16* lA0 = sA + w * 512;
  bf16* lA1 = sA + 2048 + w * 512;
  bf16* lB0 = sB + w * 512;

  const int la = L & 15;
  const int lk = (L >> 4) * 8;
  const bf16* sAr = sA + (wm + la) * 32 + lk;
  const bf16* sBr = sB + (wn + la) * 32 + lk;

  for (int kt = 0; kt < K / 32; ++kt) {
    const long k0 = (long)kt << 5;
    GLDS16(gA0 + k0, lA0);
    GLDS16(gA1 + k0, lA1);
    GLDS16(gB0 + k0, lB0);
    __syncthreads();
    bf16x8 af[4], bfm[2];
#pragma unroll
    for (int i = 0; i < 4; ++i) af[i] = *(const bf16x8*)(sAr + i * 512);
#pragma unroll
    for (int j = 0; j < 2; ++j) bfm[j] = *(const bf16x8*)(sBr + j * 512);
#pragma unroll
    for (int i = 0; i < 4; ++i)
#pragma unroll
      for (int j = 0; j < 2; ++j)
        acc[i][j] = __builtin_amdgcn_mfma_f32_16x16x32_bf16(af[i], bfm[j],
                                                            acc[i][j], 0, 0, 0);
    __syncthreads();
  }
  const long col0 = n0 + wn + la;
  const long row0 = m0 + wm + (L >> 4) * 4;
#pragma unroll
  for (int i = 0; i < 4; ++i)
#pragma unroll
    for (int j = 0; j < 2; ++j)
#pragma unroll
      for (int r = 0; r < 4; ++r)
        out0[(row0 + i * 16 + r) * N + col0 + j * 16] = acc[i][j][r];
}

// ---------------- routing + experts (R1 version, plain RMW) ----------------
__global__ void __launch_bounds__(256) route_expert(
    const float* logits, const float* X, const float* dE, const float* uE,
    float* out0) {
  __shared__ float s_vals[4][128];
  __shared__ int s_idx[4][128];
  const int w = threadIdx.x >> 6;
  const int L = threadIdx.x & 63;
  const int j = blockIdx.x * 4 + w;

  const int half = (j & 1) * 64;
  const int rx = j >> 1;
  const float vx = logits[(long)rx * 128 + half + L];
  const float vy = logits[(long)(2048 + rx) * 128 + half + L];

  int rkx = 0, rky = 0;
  for (int m = 0; m < 64; ++m) {
    const float mx = __shfl(vx, m);
    const float my = __shfl(vy, m);
    rkx += (mx > vx) || (mx == vx && m < L);
    rky += (my > vy) || (my == vy && m < L);
  }
  rkx &= 63;
  rky &= 63;
  s_vals[w][rkx] = vx;
  s_idx[w][rkx] = L;
  s_vals[w][64 + rky] = vy;
  s_idx[w][64 + rky] = L;
  __syncthreads();

  int p = 0, q = 0;
  const bool valid = (L < 20);
  if (L < 8)       { p = L;      q = 0; }
  else if (L < 12) { p = L - 8;  q = 1; }
  else if (L < 14) { p = L - 12; q = 2; }
  else if (L < 16) { p = L - 14; q = 3; }
  else if (L < 20) { p = 0;      q = L - 12; }
  const float kNegBig = -3.0e38f;
  float myv = valid ? (s_vals[w][p] + s_vals[w][64 + q]) : kNegBig;
  int mypos = valid ? (p * 64 + q) : 0x7fffffff;

  float topv[8];
  int tope[8];
#pragma unroll
  for (int r = 0; r < 8; ++r) {
    float bv = myv;
    int bp = mypos;
#pragma unroll
    for (int d = 32; d > 0; d >>= 1) {
      const float ov = __shfl_xor(bv, d);
      const int op = __shfl_xor(bp, d);
      if (ov > bv || (ov == bv && op < bp)) { bv = ov; bp = op; }
    }
    topv[r] = bv;
    const int pp = (bp >> 6) & 127, qq = bp & 63;
    tope[r] = (s_idx[w][pp] * 64 + s_idx[w][64 + qq]) & 4095;
    if (mypos == bp) myv = kNegBig;
  }

  float e[8], wsum = 0.f;
#pragma unroll
  for (int r = 0; r < 8; ++r) {
    e[r] = __expf(topv[r] - topv[0]);
    wsum += e[r];
  }
  const float winv = 1.f / wsum;

  const long xoff = (long)j * kHid + L * 16;
  float xv[16], acc[16];
#pragma unroll
  for (int v4 = 0; v4 < 4; ++v4) {
    const f32x4 xl = *(const f32x4*)(X + xoff + v4 * 4);
#pragma unroll
    for (int i = 0; i < 4; ++i) { xv[v4 * 4 + i] = xl[i]; acc[v4 * 4 + i] = 0.f; }
  }

  for (int r = 0; r < 8; ++r) {
    const long eo = (long)tope[r] * kHid + L * 16;
    float d = 0.f;
#pragma unroll
    for (int v4 = 0; v4 < 4; ++v4) {
      const f32x4 dl = *(const f32x4*)(dE + eo + v4 * 4);
#pragma unroll
      for (int i = 0; i < 4; ++i) d += dl[i] * xv[v4 * 4 + i];
    }
#pragma unroll
    for (int dd = 32; dd > 0; dd >>= 1) d += __shfl_xor(d, dd);
    const float ew = d / (1.f + __expf(-d)) * (e[r] * winv);
#pragma unroll
    for (int v4 = 0; v4 < 4; ++v4) {
      const f32x4 ul = *(const f32x4*)(uE + eo + v4 * 4);
#pragma unroll
      for (int i = 0; i < 4; ++i) acc[v4 * 4 + i] += ew * ul[i];
    }
  }

  float* po = out0 + xoff;
#pragma unroll
  for (int v4 = 0; v4 < 4; ++v4) {
    f32x4 ov = *(const f32x4*)(po + v4 * 4);
#pragma unroll
    for (int i = 0; i < 4; ++i) ov[i] += acc[v4 * 4 + i];
    *(f32x4*)(po + v4 * 4) = ov;
  }
}

extern "C" void kernel_launch(void* const* d_in, const int* in_sizes, int n_in,
                              void* d_out, int out_size, void* d_ws,
                              size_t ws_size, hipStream_t stream) {
  (void)in_sizes; (void)n_in; (void)out_size; (void)ws_size;
  const float* X  = (const float*)d_in[0];
  const float* Wg = (const float*)d_in[1];
  const float* Wu = (const float*)d_in[2];
  const float* Wd = (const float*)d_in[3];
  const float* Wr = (const float*)d_in[4];
  const float* dE = (const float*)d_in[5];
  const float* uE = (const float*)d_in[6];

  float* out0 = (float*)d_out;                  // (4096,1024) final
  float* out1 = out0 + (size_t)kTok * kHid;     // (2,4096,64) router logits

  // workspace layout (64 MiB):
  //   wsH : 32 MiB H bf16 (Wrb aliased at head; router runs before gu)
  //   Xb/Wgb/Wub/Wdb : 8 MiB each
  bf16* wsH = (bf16*)d_ws;
  bf16* Wrb = wsH;
  bf16* Xb  = wsH + (size_t)kTok * kInter;
  bf16* Wgb = Xb  + (size_t)kTok * kHid;
  bf16* Wub = Wgb + (size_t)kInter * kHid;
  bf16* Wdb = Wub + (size_t)kInter * kHid;

  dim3 blk(256);
  // 1) convert all GEMM operands to bf16 (no zeroing needed anywhere)
  k_cvt_all<<<dim3(2048, 5), blk, 0, stream>>>(X, Wg, Wu, Wd, Wr,
                                               Xb, Wgb, Wub, Wdb, Wrb);
  // 2) router logits -> out1 (plain store, 64 blocks)
  gemm_router<<<dim3(64), blk, 0, stream>>>(Xb, Wrb, out1);
  // 3) H = silu(X*Wg^T)*(X*Wu^T) -> wsH (overwrites Wrb region)
  gemm_gu<<<dim3(32, 32), blk, 0, stream>>>(Xb, Wgb, Wub, wsH);
  // 4) out0 = H*Wd^T (full-K, plain store, 512 blocks)
  gemm_down<<<dim3(16, 32), blk, 0, stream>>>(wsH, Wdb, out0);
  // 5) routing + experts, RMW out0
  route_expert<<<dim3(kTok / 4), blk, 0, stream>>>(out1, X, dE, uE, out0);
}